// Round 14
// baseline (253.245 us; speedup 1.0000x reference)
//
#include <hip/hip_runtime.h>

// Problem constants (match reference)
#define C 80
#define P 30000
#define G 800
#define BS 256
#define NB 16           // 64-px cells over [0,1024); boxes binned by CENTER
#define NC (NB * NB)    // 256 cells per class
#define PAD 224         // padded slots per (class,cell) bucket (lambda~134, +7.8 sigma)
#define MBS 128         // match block threads (one block per cell, ~134 preds)
#define GTN 384         // staged-GT cap for the 3x3 neighborhood (lambda~28)
#define HCH 8           // hist chunks per class (finale parallelism)
#define CHSZ ((P + HCH - 1) / HCH)   // 3750

// Center-binning prune (validated absmax 0.0 across rounds 1-5,7-12): IoU>0.5
// forces each box to contain the other's center in both dims, so any viable
// GT's center lies strictly inside the pred box -> candidate cells are the
// cells the pred box overlaps, and (box <= 128px, center in cell cc) those
// lie within cc+-1 per dim. Pruned pairs provably have IoU <= 0.5; validity
// re-verified with the bit-exact reference division in the epilogue.
//
// Round-14 = round-13 (never measured: container infra failure) + one fix:
// the 3x3 segment tables cs[]/cc9[] were per-thread arrays with RUNTIME
// indexing -> scratch allocation (compiler rule: runtime-indexed private
// arrays go to local memory). They are block-uniform, so they now live in
// __shared__ (tid-0 write, dynamic LDS read = broadcast, conflict-free).
//
// Structure: padded per-cell buckets delete the scan (ppack = fused
// count+scatter, one launch); match = one 128-thread block per (cell,class),
// all wave lanes share a cell (minimal divergence), 3x3-only GT staging
// (~8.8KB LDS), XCD swizzle (confirmed rounds 11/12: class slab in one L2).
// j-order preserved exactly (segment starts mirror the global cell-sorted
// order of rounds 2-12) -> argmax tie-breaks and epilogue bit-identical.
//
// Round-7 lesson kept everywhere: atomically-accumulated buffers (predCur,
// gHist) cross a KERNEL BOUNDARY before being plain-read (XCD coherence).

// rank order = score desc, then pred-index asc. Packed key is monotone in
// that order (scores >= 0 so float bits are order-preserving). key==0 means
// "no match" (needs score==0.0f AND p==P-1 — probability ~0).
__device__ __forceinline__ unsigned long long pack_key(float s, int p) {
    return ((unsigned long long)__float_as_uint(s) << 32) | (unsigned)(P - 1 - p);
}

__device__ __forceinline__ int cell_coord(float v) {
    return min(max((int)(v * (1.0f / 64.0f)), 0), NB - 1);
}

__device__ __forceinline__ int cell_of_center(float cxf, float cyf) {
    return cell_coord(cyf) * NB + cell_coord(cxf);
}

// ---------------- gt binning: one block per class (count+scan+scatter) ------
// (verbatim round 12, minus the dropped predCnt.) BS == NC == 256: thread t
// owns cell t. Zeroes this class's gtKey, gHist, predCur, ticket.
__global__ __launch_bounds__(BS) void gt_bin_kernel(
        const float* __restrict__ gt,
        unsigned short* __restrict__ gtCnt, unsigned short* __restrict__ gtOff,
        float4* __restrict__ gtBox, float* __restrict__ gtAbe,
        unsigned short* __restrict__ gtIdx,
        unsigned long long* __restrict__ gtKey, int* __restrict__ gHist,
        int* __restrict__ predCur, unsigned int* __restrict__ doneCnt) {
    __shared__ int h[NC], cur[NC];
    __shared__ int gcell[G];
    const int c = blockIdx.x, tid = threadIdx.x;
    h[tid] = 0;
    predCur[c * NC + tid] = 0;                                       // folded init
    if (c == 0 && tid == 0) *doneCnt = 0u;                           // folded init
    for (int i = tid; i < G; i += BS) gtKey[c * G + i] = 0ull;       // folded init
    for (int j = tid; j < 1024; j += BS) gHist[c * 1024 + j] = 0;    // folded init
    __syncthreads();
    for (int i = tid; i < G; i += BS) {
        const float* r = gt + ((size_t)c * G + i) * 7;
        int cl = cell_of_center(0.5f * (r[3] + r[5]), 0.5f * (r[4] + r[6]));
        gcell[i] = cl;
        atomicAdd(&h[cl], 1);
    }
    __syncthreads();
    const int v = h[tid];
    cur[tid] = v;
    __syncthreads();
    for (int o = 1; o < NC; o <<= 1) {   // inclusive scan, 8 steps
        int t = (tid >= o) ? cur[tid - o] : 0;
        __syncthreads();
        cur[tid] += t;
        __syncthreads();
    }
    const int excl = cur[tid] - v;
    gtOff[c * NC + tid] = (unsigned short)excl;
    gtCnt[c * NC + tid] = (unsigned short)v;
    __syncthreads();
    cur[tid] = excl;
    __syncthreads();
    for (int i = tid; i < G; i += BS) {
        const float* r = gt + ((size_t)c * G + i) * 7;   // L1-hot (2nd pass)
        float x1 = r[3], y1 = r[4], x2 = r[5], y2 = r[6];
        int slot = atomicAdd(&cur[gcell[i]], 1);
        gtBox[c * G + slot] = make_float4(x1, y1, x2, y2);
        // area + eps pre-folded: cross-compare uses sb = A + (area_g + eps);
        // the -inter terms of the two denominators cancel algebraically.
        gtAbe[c * G + slot] = __fadd_rn(__fmul_rn(__fsub_rn(x2, x1), __fsub_rn(y2, y1)), 1e-9f);
        gtIdx[c * G + slot] = (unsigned short)i;
    }
}

// ---------------- ppack: fused count + padded-bucket scatter ----------
// One coalesced pass over preds: cell -> LDS-aggregated local rank -> one
// global atomic per nonempty cell per block reserves the bucket range ->
// write the ushort pred index into pIdxS[c][cell][base+lr]. No scan, no
// second pass. predCur doubles as the final per-cell count (consumed only
// in the NEXT launch). idx>=PAD writes dropped (clamp; absmax-guarded).
__global__ __launch_bounds__(BS) void ppack_kernel(
        const float* __restrict__ pred, int* __restrict__ predCur,
        unsigned short* __restrict__ pIdxS) {
    __shared__ int h[NC], base[NC];
    const int c = blockIdx.y, tid = threadIdx.x;
    h[tid] = 0;
    __syncthreads();
    int p = blockIdx.x * BS + tid;
    int cellv = 0, lr = 0;
    if (p < P) {
        const float* r = pred + ((size_t)c * P + p) * 7;
        cellv = cell_of_center(0.5f * (r[3] + r[5]), 0.5f * (r[4] + r[6]));
        lr = atomicAdd(&h[cellv], 1);   // LDS, local rank
    }
    __syncthreads();
    if (h[tid]) base[tid] = atomicAdd(&predCur[c * NC + tid], h[tid]);
    __syncthreads();
    if (p < P) {
        int idx = base[cellv] + lr;
        if (idx < PAD)
            pIdxS[((size_t)(c * NC + cellv)) * PAD + idx] = (unsigned short)p;
    }
}

// ---------------- match: one block per (cell, class) ----------
// 1D grid of 20480, XCD-swizzled: id = (c%8) + 8*(cell + 256*(c/8)) -> all
// 256 cells of a class on one XCD (slab L2-resident; confirmed rounds
// 11/12). All lanes of a wave process preds of the SAME cell -> bounds
// divergence is box-jitter only. Stage only the 3x3 GT neighborhood with
// per-cell segment starts in LDS — the j sequence (row-major neighbor
// cells, intra-cell gt_bin order) is IDENTICAL to the global cell-sorted
// order of rounds 2-12, so argmax tie-breaks and the bit-exact epilogue
// are unchanged. Empty cells (count 0) exit immediately.
__global__ __launch_bounds__(MBS) void match14_kernel(
        const float* __restrict__ pred, const unsigned short* __restrict__ pIdxS,
        const int* __restrict__ predCur,
        const unsigned short* __restrict__ gtOff, const unsigned short* __restrict__ gtCnt,
        const float4* __restrict__ gtBox, const float* __restrict__ gtAbe,
        const unsigned short* __restrict__ gtIdx,
        unsigned long long* __restrict__ gtKey) {
    __shared__ float4 sB[GTN];              // 6.0 KB
    __shared__ float  sE[GTN];              // 1.5 KB
    __shared__ unsigned short sG[GTN];      // 0.75 KB
    __shared__ int sCs[9], sCc[9];          // segment starts/counts (uniform)
    const int id  = blockIdx.x;
    const int xcd = id & 7;
    const int q   = id >> 3;
    const int cell = q & 255;
    const int c    = xcd + 8 * (q >> 8);
    const int tid = threadIdx.x;

    const int n = min(predCur[c * NC + cell], PAD);   // finalized in ppack launch
    if (n == 0) return;                               // block-uniform exit

    const int cx = cell & (NB - 1), cy = cell >> 4;
    // stage 3x3 neighborhood; segment table computed uniformly, stored in LDS
    int total = 0;
    #pragma unroll
    for (int dy = -1; dy <= 1; ++dy) {
        #pragma unroll
        for (int dx = -1; dx <= 1; ++dx) {
            const int r9 = (dy + 1) * 3 + (dx + 1);
            int yy = cy + dy, xx = cx + dx;
            int off = 0, cnt = 0;
            if (yy >= 0 && yy < NB && xx >= 0 && xx < NB) {
                int ncell = yy * NB + xx;
                off = gtOff[c * NC + ncell];
                cnt = gtCnt[c * NC + ncell];
            }
            if (total + cnt > GTN) cnt = GTN - total;   // clamp (absmax-guarded)
            if (tid == 0) { sCs[r9] = total; sCc[r9] = cnt; }
            for (int i = tid; i < cnt; i += MBS) {
                sB[total + i] = gtBox[c * G + off + i];
                sE[total + i] = gtAbe[c * G + off + i];
                sG[total + i] = gtIdx[c * G + off + i];
            }
            total += cnt;   // uniform across threads
        }
    }
    if (total == 0) return;   // uniform: no GT can match these preds
    __syncthreads();

    const size_t cp = (size_t)c * P;
    const unsigned short* slotp = pIdxS + ((size_t)(c * NC + cell)) * PAD;
    for (int i = tid; i < n; i += MBS) {
        const int p = slotp[i];
        const float* r = pred + (cp + p) * 7;     // L2-hot gather (swizzle)
        float ax1 = r[3], ay1 = r[4], ax2 = r[5], ay2 = r[6];
        float A = __fmul_rn(__fsub_rn(ax2, ax1), __fsub_rn(ay2, ay1));
        // candidate cells: those the pred box overlaps — within cc+-1 (lemma)
        const int x0 = cell_coord(ax1), x1g = cell_coord(ax2);
        const int y0 = cell_coord(ay1), y1g = cell_coord(ay2);
        float IN = 0.0f, SB = 1.0f;
        int mj = -1;
        for (int yy = y0; yy <= y1g; ++yy) {
            const int r3 = min(max(yy - (cy - 1), 0), 2);   // in [0,2] by lemma
            const int lo = min(max(x0  - (cx - 1), 0), 2);
            const int hi = min(max(x1g - (cx - 1), 0), 2);
            const int jb = sCs[r3 * 3 + lo];                 // LDS broadcast
            const int je = sCs[r3 * 3 + hi] + sCc[r3 * 3 + hi];
            #pragma unroll 2
            for (int j = jb; j < je; ++j) {
                float4 b = sB[j];
                float lx = fmaxf(ax1, b.x), ly = fmaxf(ay1, b.y);
                float rx = fminf(ax2, b.z), ry = fminf(ay2, b.w);
                float wx = fmaxf(__fsub_rn(rx, lx), 0.0f);
                float wy = fmaxf(__fsub_rn(ry, ly), 0.0f);
                float in = __fmul_rn(wx, wy);
                float sb = __fadd_rn(A, sE[j]);
                bool  up = __fmul_rn(in, SB) > __fmul_rn(IN, sb);
                IN = up ? in : IN; SB = up ? sb : SB; mj = up ? j : mj;
            }
        }
        if (IN > 0.0f) {   // zero-inter preds can never be valid
            float4 b = sB[mj];
            float area = __fmul_rn(__fsub_rn(b.z, b.x), __fsub_rn(b.w, b.y));
            float dn = __fadd_rn(__fsub_rn(__fadd_rn(A, area), IN), 1e-9f);
            float iou = __fdiv_rn(IN, dn);   // exact reference value
            if (iou > 0.5f) {
                float sscore = r[2];         // rare path, L1-hot line
                atomicMax(&gtKey[c * G + sG[mj]], pack_key(sscore, p));
            }
        }
    }
}

// ---------------- histf: compact+sort (x8 redundant) + chunked hist ------
// (verbatim round 12 — passed.) gHist consumed only in the NEXT launch.
__global__ __launch_bounds__(BS) void histf_kernel(
        const float* __restrict__ pred,
        const unsigned long long* __restrict__ gtKey,
        int* __restrict__ gHist, int* __restrict__ sortT) {
    __shared__ unsigned long long k[G];     // 6.4 KB compacted keys
    __shared__ unsigned long long sk[1024]; // 8 KB sorted-desc keys (pad=0)
    __shared__ int h[1024];                 // 4 KB local hist
    __shared__ int cnt;
    const int c = blockIdx.y, chunk = blockIdx.x, tid = threadIdx.x;

    if (tid == 0) cnt = 0;
    for (int j = tid; j < 1024; j += BS) { sk[j] = 0ull; h[j] = 0; }
    __syncthreads();
    for (int i = tid; i < G; i += BS) {
        unsigned long long key = gtKey[c * G + i];
        if (key != 0ull) k[atomicAdd(&cnt, 1)] = key;
    }
    __syncthreads();
    const int T = cnt;
    if (chunk == 0 && tid == 0) sortT[c] = T;

    for (int t = tid; t < T; t += BS) {
        unsigned long long key = k[t];
        int pos = 0;
        for (int u = 0; u < T; ++u) pos += (k[u] > key) ? 1 : 0;
        sk[pos] = key;
    }
    __syncthreads();

    const int start = chunk * CHSZ;
    const int end   = min(start + CHSZ, P);
    const float* pr = pred + (size_t)c * P * 7;
    for (int i = start + tid; i < end; i += BS) {
        unsigned long long kq =
            ((unsigned long long)__float_as_uint(pr[(size_t)i * 7 + 2]) << 32)
            | (unsigned)(P - 1 - i);
        int lo = 0;   // count of sorted-desc keys > kq (pads are 0, never > kq)
        #pragma unroll
        for (int step = 512; step > 0; step >>= 1)
            if (sk[lo + step - 1] > kq) lo += step;
        atomicAdd(&h[lo], 1);
    }
    __syncthreads();
    for (int j = tid; j < 1024; j += BS)
        if (h[j]) atomicAdd(&gHist[c * 1024 + j], h[j]);   // no-return
}

// ---------------- ap + mean: prefix over hist + closed-form + last-block ----
// (verbatim round 12 — passed.)
__global__ __launch_bounds__(BS) void ap2m_kernel(
        const int* __restrict__ sortT, const int* __restrict__ gHist,
        float* __restrict__ ap, unsigned int* __restrict__ doneCnt,
        float* __restrict__ out) {
    __shared__ int ha[1024];
    __shared__ int hb[1024];
    __shared__ float red[BS];
    const int c = blockIdx.x, tid = threadIdx.x;
    const int T = sortT[c];
    for (int j = tid; j < 1024; j += BS) ha[j] = gHist[c * 1024 + j];
    __syncthreads();
    int* src = ha; int* dst = hb;
    for (int o = 1; o < 1024; o <<= 1) {
        for (int j = tid; j < 1024; j += BS)
            dst[j] = src[j] + ((j >= o) ? src[j - o] : 0);
        __syncthreads();
        int* tmp = src; src = dst; dst = tmp;
    }
    float sum = 0.0f;
    for (int s = tid; s < T; s += BS) {
        int r = src[s] - 1;          // inclusive prefix minus self
        if (r >= 1) {
            float kf  = (float)(s + 1);
            float km  = (float)s;
            float ri  = __fdiv_rn(kf, 800.0f);
            float rim = __fdiv_rn(km, 800.0f);
            float pi  = __fdiv_rn(kf, (float)(r + 1));
            float pim = __fdiv_rn(km, (float)r);
            sum = __fadd_rn(sum,
                  __fmul_rn(__fmul_rn(__fsub_rn(ri, rim), __fadd_rn(pi, pim)), 0.5f));
        }
    }
    red[tid] = sum;
    __syncthreads();
    for (int s2 = BS / 2; s2 > 0; s2 >>= 1) {
        if (tid < s2) red[tid] = __fadd_rn(red[tid], red[tid + s2]);
        __syncthreads();
    }
    if (tid == 0) {
        ap[c] = red[0];
        __threadfence();                         // publish ap[c] device-wide
        unsigned int t = atomicAdd(doneCnt, 1u); // ticket
        if (t == C - 1) {                        // last block finishes the mean
            __threadfence();                     // acquire all ap[] writes
            float s = 0.0f;
            for (int c2 = 0; c2 < C; ++c2) s = __fadd_rn(s, ap[c2]);
            out[0] = __fdiv_rn(s, 80.0f);
        }
    }
}

extern "C" void kernel_launch(void* const* d_in, const int* in_sizes, int n_in,
                              void* d_out, int out_size, void* d_ws, size_t ws_size,
                              hipStream_t stream) {
    const float* pred = (const float*)d_in[0];   // [C, P, 7] f32
    const float* gt   = (const float*)d_in[1];   // [C, G, 7] f32
    float* out = (float*)d_out;

    // Workspace layout — 11,587,584 B total. Re-poisoned 0xAA each call —
    // gt_bin (folded inits: gtKey, gHist, predCur, doneCnt) / ppack (pIdxS
    // live slots; dead slots never read: match clamps by predCur count)
    // rewrite everything read-before-write.
    char* ws = (char*)d_ws;
    int*                sortT      = (int*)               (ws + 0);         //     320 B
    float*              ap         = (float*)             (ws + 512);       //     320 B
    unsigned int*       doneCnt    = (unsigned int*)      (ws + 896);       //       4 B
    int*                predCur    = (int*)               (ws + 1024);      //  81920 B
    unsigned short*     gtCnt      = (unsigned short*)    (ws + 82944);     //  40960 B
    unsigned short*     gtOff      = (unsigned short*)    (ws + 123904);    //  40960 B
    unsigned short*     gtIdx      = (unsigned short*)    (ws + 164864);    // 128000 B
    float*              gtAbe      = (float*)             (ws + 292864);    // 256000 B
    float4*             gtBox      = (float4*)            (ws + 548864);    // 1.024 MB (16-aligned)
    unsigned long long* gtKey      = (unsigned long long*)(ws + 1572864);   // 512000 B
    int*                gHist      = (int*)               (ws + 2084864);   // 327680 B
    unsigned short*     pIdxS      = (unsigned short*)    (ws + 2412544);   // 9.175 MB
    // end: 11587584 B

    const int P_BLK = (P + BS - 1) / BS;       // 118

    gt_bin_kernel<<<C, BS, 0, stream>>>(gt, gtCnt, gtOff, gtBox, gtAbe, gtIdx,
                                        gtKey, gHist, predCur, doneCnt);
    ppack_kernel<<<dim3(P_BLK, C), BS, 0, stream>>>(pred, predCur, pIdxS);
    match14_kernel<<<NC * C, MBS, 0, stream>>>(pred, pIdxS, predCur, gtOff, gtCnt,
                                               gtBox, gtAbe, gtIdx, gtKey);
    histf_kernel<<<dim3(HCH, C), BS, 0, stream>>>(pred, gtKey, gHist, sortT);
    ap2m_kernel<<<C, BS, 0, stream>>>(sortT, gHist, ap, doneCnt, out);
}

// Round 15
// 228.045 us; speedup vs baseline: 1.1105x; 1.1105x over previous
//
#include <hip/hip_runtime.h>

// Problem constants (match reference)
#define C 80
#define P 30000
#define G 800
#define BS 256
#define NB 16          // 64-px cells over [0,1024); boxes binned by CENTER
#define NC (NB * NB)   // 256 cells per class
#define PPT 8          // preds per thread in match
#define TPB (BS * PPT) // 2048 preds per match block (block-local sort granule)
#define MPART ((P + TPB - 1) / TPB)   // 15 parts per class
#define HCH 8          // hist chunks per class (finale parallelism)
#define CHSZ ((P + HCH - 1) / HCH)   // 3750

// Center-binning prune (validated absmax 0.0 across rounds 1-5,7-12,14):
// IoU > 0.5 forces each box to contain the other's center in both dims ->
// any viable GT's center lies strictly inside the pred box -> candidate
// cells are exactly the cells the pred box overlaps. Pruned pairs provably
// have IoU <= 0.5; validity re-verified with the bit-exact reference
// division in the epilogue.
//
// Round-15 = round 8 (227.6us, best 4-launch structure) + ONE delta: XCD
// swizzle on match8's grid. The launch ledger across 15 rounds shows every
// extra plumbing launch costs ~15-20us against a ~100us fixed harness
// floor, so the global-sort family (match 73us but 5-6 launches) never
// beat round 7/8. The only zero-launch-cost lever proven on this problem
// is the XCD swizzle (rounds 11/12: FETCH 172->39MB): round-8's match8
// showed FETCH 114MB = 1.7x pred because grid (15,80) scattered a class's
// 15 blocks across all 8 XCDs — phase-B's sorted-order re-gather missed
// L2. id = (c%8) + 8*(part + 15*(c/8)) puts all 15 parts of a class on
// one XCD: phase A pulls the 840KB slab into that L2 once; phase B hits
// L2 (~200cy) instead of HBM (~900cy). Pure block remap — correctness
// unaffected; all kernels otherwise verbatim from the passing round 8.
//
// Granularity ledger (why match8's block-local sort, not the extremes):
// TPB=1024 slab-in-LDS -> 4 preds/cell, wave spans ~16 cells, divergence
// (round 9, 101us); one-block-per-cell -> ~1 pred/thread, serialized
// 9-segment prologue dominates (round 14, 98.6us); TPB=2048 block-local
// sort = ~9 preds/cell, moderate coherence, staging amortized (96-101us,
// now minus the L2-miss tax).
//
// Round-7 lesson kept: gHist crosses a KERNEL BOUNDARY before consumption
// (cross-XCD L2 non-coherence); histf/ap2m verbatim from passing rounds.

// rank order = score desc, then pred-index asc. Packed key is monotone in
// that order (scores >= 0 so float bits are order-preserving). key==0 means
// "no match" (needs score==0.0f AND p==P-1 — probability ~0).
__device__ __forceinline__ unsigned long long pack_key(float s, int p) {
    return ((unsigned long long)__float_as_uint(s) << 32) | (unsigned)(P - 1 - p);
}

__device__ __forceinline__ int cell_coord(float v) {
    return min(max((int)(v * (1.0f / 64.0f)), 0), NB - 1);
}

__device__ __forceinline__ int cell_of_center(float cxf, float cyf) {
    return cell_coord(cyf) * NB + cell_coord(cxf);
}

// ---------------- gt binning: one block per class (count+scan+scatter) ------
// (verbatim round 8 — passed.) BS == NC == 256: thread t owns cell t. Also
// zeroes this class's gtKey, gHist slab, and the global ticket.
__global__ __launch_bounds__(BS) void gt_bin_kernel(
        const float* __restrict__ gt,
        unsigned short* __restrict__ gtCnt, unsigned short* __restrict__ gtOff,
        float4* __restrict__ gtBox, float* __restrict__ gtAbe,
        unsigned short* __restrict__ gtIdx,
        unsigned long long* __restrict__ gtKey, int* __restrict__ gHist,
        unsigned int* __restrict__ doneCnt) {
    __shared__ int h[NC], cur[NC];
    __shared__ int gcell[G];
    const int c = blockIdx.x, tid = threadIdx.x;
    h[tid] = 0;
    if (c == 0 && tid == 0) *doneCnt = 0u;                           // folded init
    for (int i = tid; i < G; i += BS) gtKey[c * G + i] = 0ull;       // folded init
    for (int j = tid; j < 1024; j += BS) gHist[c * 1024 + j] = 0;    // folded init
    __syncthreads();
    for (int i = tid; i < G; i += BS) {
        const float* r = gt + ((size_t)c * G + i) * 7;
        int cl = cell_of_center(0.5f * (r[3] + r[5]), 0.5f * (r[4] + r[6]));
        gcell[i] = cl;
        atomicAdd(&h[cl], 1);
    }
    __syncthreads();
    const int v = h[tid];
    cur[tid] = v;
    __syncthreads();
    for (int o = 1; o < NC; o <<= 1) {   // inclusive scan, 8 steps
        int t = (tid >= o) ? cur[tid - o] : 0;
        __syncthreads();
        cur[tid] += t;
        __syncthreads();
    }
    const int excl = cur[tid] - v;
    gtOff[c * NC + tid] = (unsigned short)excl;
    gtCnt[c * NC + tid] = (unsigned short)v;
    __syncthreads();
    cur[tid] = excl;
    __syncthreads();
    for (int i = tid; i < G; i += BS) {
        const float* r = gt + ((size_t)c * G + i) * 7;   // L1-hot (2nd pass)
        float x1 = r[3], y1 = r[4], x2 = r[5], y2 = r[6];
        int slot = atomicAdd(&cur[gcell[i]], 1);
        gtBox[c * G + slot] = make_float4(x1, y1, x2, y2);
        // area + eps pre-folded: cross-compare uses sb = A + (area_g + eps);
        // the -inter terms of the two denominators cancel algebraically.
        gtAbe[c * G + slot] = __fadd_rn(__fmul_rn(__fsub_rn(x2, x1), __fsub_rn(y2, y1)), 1e-9f);
        gtIdx[c * G + slot] = (unsigned short)i;
    }
}

// ---------------- match: streamed preds + block-local cell sort + swizzle --
// Phase A (verbatim round 8): coalesced cell pass + LDS hist; 256-bin scan;
// scatter local indices into cell-sorted order. Phase B: pair loop over the
// cells OVERLAPPED BY THE PRED BOX in sorted order; pred re-gather now hits
// the class slab in THIS XCD's L2 (swizzle). Pair arithmetic, GT order,
// epilogue bit-identical to proven rounds 2-8.
__global__ __launch_bounds__(BS) void match8s_kernel(
        const float* __restrict__ pred,
        const unsigned short* __restrict__ gtOff, const unsigned short* __restrict__ gtCnt,
        const float4* __restrict__ gtBox, const float* __restrict__ gtAbe,
        const unsigned short* __restrict__ gtIdx,
        unsigned long long* __restrict__ gtKey) {
    __shared__ float4 sB[G];                        // 12.8 KB
    __shared__ float  sE[G];                        //  3.2 KB
    __shared__ unsigned short sG[G];                //  1.6 KB
    __shared__ unsigned short sOff[NC], sCnt[NC];   //  1.0 KB
    __shared__ unsigned short sIdx[TPB];            //  4.0 KB
    __shared__ int hcnt[NC], bb[NC];                //  2.0 KB
    // XCD swizzle: all MPART parts of a class share id%8 -> one XCD's L2
    const int id   = blockIdx.x;
    const int xcd  = id & 7;
    const int q    = id >> 3;
    const int part = q % MPART;
    const int c    = xcd + 8 * (q / MPART);
    const int tid  = threadIdx.x;
    const int p0   = part * TPB;
    const int cntP = min(TPB, P - p0);

    for (int i = tid; i < G; i += BS) {
        sB[i] = gtBox[c * G + i];
        sE[i] = gtAbe[c * G + i];
        sG[i] = gtIdx[c * G + i];
    }
    sOff[tid] = gtOff[c * NC + tid];   // BS == NC
    sCnt[tid] = gtCnt[c * NC + tid];
    hcnt[tid] = 0;
    __syncthreads();

    const size_t cp = (size_t)c * P;

    // ---- phase A: coalesced cell computation + block histogram ----
    unsigned char  cellA[PPT];
    unsigned short lrA[PPT];
    #pragma unroll
    for (int rep = 0; rep < PPT; ++rep) {
        const int li = rep * BS + tid;
        const int p  = p0 + li;
        int cell = 0, lr = 0;
        if (p < P) {
            const float* r = pred + (cp + p) * 7;
            cell = cell_of_center(0.5f * (r[3] + r[5]), 0.5f * (r[4] + r[6]));
            lr = atomicAdd(&hcnt[cell], 1);
        }
        cellA[rep] = (unsigned char)cell;
        lrA[rep] = (unsigned short)lr;
    }
    __syncthreads();

    // ---- scan 256 bins (proven pattern) -> exclusive base in bb ----
    const int v = hcnt[tid];
    __syncthreads();
    for (int o = 1; o < NC; o <<= 1) {
        int t = (tid >= o) ? hcnt[tid - o] : 0;
        __syncthreads();
        hcnt[tid] += t;
        __syncthreads();
    }
    bb[tid] = hcnt[tid] - v;
    __syncthreads();

    // ---- scatter local indices into cell-sorted order ----
    #pragma unroll
    for (int rep = 0; rep < PPT; ++rep) {
        const int li = rep * BS + tid;
        if (p0 + li < P) sIdx[bb[cellA[rep]] + lrA[rep]] = (unsigned short)li;
    }
    __syncthreads();

    // ---- phase B: pair loop over pred-box-overlapped cells, sorted order ----
    #pragma unroll 1
    for (int rep = 0; rep < PPT; ++rep) {
        const int si = rep * BS + tid;
        if (si < cntP) {
            const int li = sIdx[si];
            const int p  = p0 + li;
            const float* r = pred + (cp + p) * 7;     // L2-hot re-gather (swizzle)
            float ax1 = r[3], ay1 = r[4], ax2 = r[5], ay2 = r[6];
            float A = __fmul_rn(__fsub_rn(ax2, ax1), __fsub_rn(ay2, ay1));
            // candidate cells: those the pred box overlaps (any GT center
            // with iou>0.5 lies strictly inside the pred box)
            const int x0 = cell_coord(ax1), x1 = cell_coord(ax2);
            const int y0 = cell_coord(ay1), y1 = cell_coord(ay2);
            float IN = 0.0f, SB = 1.0f;
            int mj = -1;
            for (int yy = y0; yy <= y1; ++yy) {
                const int rowb = yy * NB;
                const int jb = sOff[rowb + x0];
                const int je = sOff[rowb + x1] + sCnt[rowb + x1];
                #pragma unroll 2
                for (int j = jb; j < je; ++j) {
                    float4 b = sB[j];
                    float lx = fmaxf(ax1, b.x), ly = fmaxf(ay1, b.y);
                    float rx = fminf(ax2, b.z), ry = fminf(ay2, b.w);
                    float wx = fmaxf(__fsub_rn(rx, lx), 0.0f);
                    float wy = fmaxf(__fsub_rn(ry, ly), 0.0f);
                    float in = __fmul_rn(wx, wy);
                    float sb = __fadd_rn(A, sE[j]);
                    bool  up = __fmul_rn(in, SB) > __fmul_rn(IN, sb);
                    IN = up ? in : IN; SB = up ? sb : SB; mj = up ? j : mj;
                }
            }
            if (IN > 0.0f) {   // zero-inter preds can never be valid
                float4 b = sB[mj];
                float area = __fmul_rn(__fsub_rn(b.z, b.x), __fsub_rn(b.w, b.y));
                float dn = __fadd_rn(__fsub_rn(__fadd_rn(A, area), IN), 1e-9f);
                float iou = __fdiv_rn(IN, dn);   // exact reference value
                if (iou > 0.5f) {
                    float sscore = r[2];         // rare path
                    atomicMax(&gtKey[c * G + sG[mj]], pack_key(sscore, p));
                }
            }
        }
    }
}

// ---------------- histf: compact+sort (x8 redundant) + chunked hist ------
// (verbatim round 8 — passed.) gHist consumed only in the NEXT launch.
__global__ __launch_bounds__(BS) void histf_kernel(
        const float* __restrict__ pred,
        const unsigned long long* __restrict__ gtKey,
        int* __restrict__ gHist, int* __restrict__ sortT) {
    __shared__ unsigned long long k[G];     // 6.4 KB compacted keys
    __shared__ unsigned long long sk[1024]; // 8 KB sorted-desc keys (pad=0)
    __shared__ int h[1024];                 // 4 KB local hist
    __shared__ int cnt;
    const int c = blockIdx.y, chunk = blockIdx.x, tid = threadIdx.x;

    if (tid == 0) cnt = 0;
    for (int j = tid; j < 1024; j += BS) { sk[j] = 0ull; h[j] = 0; }
    __syncthreads();
    for (int i = tid; i < G; i += BS) {
        unsigned long long key = gtKey[c * G + i];
        if (key != 0ull) k[atomicAdd(&cnt, 1)] = key;
    }
    __syncthreads();
    const int T = cnt;
    if (chunk == 0 && tid == 0) sortT[c] = T;

    for (int t = tid; t < T; t += BS) {
        unsigned long long key = k[t];
        int pos = 0;
        for (int u = 0; u < T; ++u) pos += (k[u] > key) ? 1 : 0;
        sk[pos] = key;
    }
    __syncthreads();

    const int start = chunk * CHSZ;
    const int end   = min(start + CHSZ, P);
    const float* pr = pred + (size_t)c * P * 7;
    for (int i = start + tid; i < end; i += BS) {
        unsigned long long kq =
            ((unsigned long long)__float_as_uint(pr[(size_t)i * 7 + 2]) << 32)
            | (unsigned)(P - 1 - i);
        int lo = 0;   // count of sorted-desc keys > kq (pads are 0, never > kq)
        #pragma unroll
        for (int step = 512; step > 0; step >>= 1)
            if (sk[lo + step - 1] > kq) lo += step;
        atomicAdd(&h[lo], 1);
    }
    __syncthreads();
    for (int j = tid; j < 1024; j += BS)
        if (h[j]) atomicAdd(&gHist[c * 1024 + j], h[j]);   // no-return
}

// ---------------- ap + mean: prefix over hist + closed-form + last-block ----
// (verbatim round 8 — passed.)
__global__ __launch_bounds__(BS) void ap2m_kernel(
        const int* __restrict__ sortT, const int* __restrict__ gHist,
        float* __restrict__ ap, unsigned int* __restrict__ doneCnt,
        float* __restrict__ out) {
    __shared__ int ha[1024];
    __shared__ int hb[1024];
    __shared__ float red[BS];
    const int c = blockIdx.x, tid = threadIdx.x;
    const int T = sortT[c];
    for (int j = tid; j < 1024; j += BS) ha[j] = gHist[c * 1024 + j];
    __syncthreads();
    int* src = ha; int* dst = hb;
    for (int o = 1; o < 1024; o <<= 1) {
        for (int j = tid; j < 1024; j += BS)
            dst[j] = src[j] + ((j >= o) ? src[j - o] : 0);
        __syncthreads();
        int* tmp = src; src = dst; dst = tmp;
    }
    float sum = 0.0f;
    for (int s = tid; s < T; s += BS) {
        int r = src[s] - 1;          // inclusive prefix minus self
        if (r >= 1) {
            float kf  = (float)(s + 1);
            float km  = (float)s;
            float ri  = __fdiv_rn(kf, 800.0f);
            float rim = __fdiv_rn(km, 800.0f);
            float pi  = __fdiv_rn(kf, (float)(r + 1));
            float pim = __fdiv_rn(km, (float)r);
            sum = __fadd_rn(sum,
                  __fmul_rn(__fmul_rn(__fsub_rn(ri, rim), __fadd_rn(pi, pim)), 0.5f));
        }
    }
    red[tid] = sum;
    __syncthreads();
    for (int s2 = BS / 2; s2 > 0; s2 >>= 1) {
        if (tid < s2) red[tid] = __fadd_rn(red[tid], red[tid + s2]);
        __syncthreads();
    }
    if (tid == 0) {
        ap[c] = red[0];
        __threadfence();                         // publish ap[c] device-wide
        unsigned int t = atomicAdd(doneCnt, 1u); // ticket
        if (t == C - 1) {                        // last block finishes the mean
            __threadfence();                     // acquire all ap[] writes
            float s = 0.0f;
            for (int c2 = 0; c2 < C; ++c2) s = __fadd_rn(s, ap[c2]);
            out[0] = __fdiv_rn(s, 80.0f);
        }
    }
}

extern "C" void kernel_launch(void* const* d_in, const int* in_sizes, int n_in,
                              void* d_out, int out_size, void* d_ws, size_t ws_size,
                              hipStream_t stream) {
    const float* pred = (const float*)d_in[0];   // [C, P, 7] f32
    const float* gt   = (const float*)d_in[1];   // [C, G, 7] f32
    float* out = (float*)d_out;

    // Workspace layout — 2,330,624 B total (verbatim round 8). Re-poisoned
    // 0xAA each call — gt_bin (incl. folded inits: gtKey, gHist, doneCnt)
    // rewrites everything read-before-write; sortT written by histf before
    // ap2m reads it.
    char* ws = (char*)d_ws;
    int*                sortT      = (int*)               (ws + 0);         //     320 B
    float*              ap         = (float*)             (ws + 512);       //     320 B
    unsigned int*       doneCnt    = (unsigned int*)      (ws + 896);       //       4 B
    unsigned short*     gtCnt      = (unsigned short*)    (ws + 1024);      //  40960 B
    unsigned short*     gtOff      = (unsigned short*)    (ws + 41984);     //  40960 B
    unsigned short*     gtIdx      = (unsigned short*)    (ws + 82944);     // 128000 B
    float*              gtAbe      = (float*)             (ws + 210944);    // 256000 B
    float4*             gtBox      = (float4*)            (ws + 466944);    // 1.024 MB (16-aligned)
    unsigned long long* gtKey      = (unsigned long long*)(ws + 1490944);   // 512000 B
    int*                gHist      = (int*)               (ws + 2002944);   // 327680 B
    // end: 2330624 B

    gt_bin_kernel<<<C, BS, 0, stream>>>(gt, gtCnt, gtOff, gtBox, gtAbe, gtIdx,
                                        gtKey, gHist, doneCnt);
    match8s_kernel<<<MPART * C, BS, 0, stream>>>(pred, gtOff, gtCnt, gtBox,
                                                 gtAbe, gtIdx, gtKey);
    histf_kernel<<<dim3(HCH, C), BS, 0, stream>>>(pred, gtKey, gHist, sortT);
    ap2m_kernel<<<C, BS, 0, stream>>>(sortT, gHist, ap, doneCnt, out);
}